// Round 3
// baseline (2655.097 us; speedup 1.0000x reference)
//
#include <hip/hip_runtime.h>

#define NB 32
#define NC 32
#define NNODE 512
#define NT 168
#define NTO 156
#define NQ 39          // NTO / 4
#define NEMB 40
#define KNEI 20
#define NADJ 21        // 20 neighbors + diagonal

static_assert(NTO == 4 * NQ, "t quads");

typedef __attribute__((ext_vector_type(8))) short bf16x8;
typedef __attribute__((ext_vector_type(16))) float f32x16;

// ---------------------------------------------------------------- helpers
__device__ __forceinline__ float fast_tanh(float x) {
  float e = __expf(2.0f * x);
  return 1.0f - 2.0f / (e + 1.0f);
}
__device__ __forceinline__ float fast_sigmoid(float x) {
  return 1.0f / (1.0f + __expf(-x));
}
__device__ __forceinline__ unsigned short f2b(float v) {   // f32 -> bf16 RNE
  unsigned int u = __float_as_uint(v);
  unsigned int r = (u + 0x7FFFu + ((u >> 16) & 1u)) >> 16;
  return (unsigned short)r;
}
__device__ __forceinline__ float4 bf4load(const unsigned short* p) {
  ushort4 u = *reinterpret_cast<const ushort4*>(p);
  float4 r;
  r.x = __uint_as_float((unsigned int)u.x << 16);
  r.y = __uint_as_float((unsigned int)u.y << 16);
  r.z = __uint_as_float((unsigned int)u.z << 16);
  r.w = __uint_as_float((unsigned int)u.w << 16);
  return r;
}

// ---------------------------------------------------------------- G1: node embeddings
__global__ __launch_bounds__(128) void g1_kernel(
    const float* __restrict__ emb1, const float* __restrict__ emb2,
    const float* __restrict__ W1, const float* __restrict__ b1,
    const float* __restrict__ W2, const float* __restrict__ b2,
    const int* __restrict__ idx, float* __restrict__ n1, float* __restrict__ n2) {
  const int v = blockIdx.x;
  const int tid = threadIdx.x;
  const int iv = idx[v];
  if (tid < NEMB) {
    float s = b1[tid];
    const float* er = emb1 + iv * NEMB;
    const float* wr = W1 + tid * NEMB;
    for (int f = 0; f < NEMB; ++f) s = fmaf(er[f], wr[f], s);
    n1[v * NEMB + tid] = tanhf(3.0f * s);
  } else if (tid >= 64 && tid < 64 + NEMB) {
    const int e = tid - 64;
    float s = b2[e];
    const float* er = emb2 + iv * NEMB;
    const float* wr = W2 + e * NEMB;
    for (int f = 0; f < NEMB; ++f) s = fmaf(er[f], wr[f], s);
    n2[v * NEMB + e] = tanhf(3.0f * s);
  }
}

// ---------------------------------------------------------------- G2: adjacency row + topk + normalize
__global__ __launch_bounds__(256) void g2_kernel(
    const float* __restrict__ n1, const float* __restrict__ n2,
    int* __restrict__ cols, float* __restrict__ wts) {
  const int v = blockIdx.x;
  const int tid = threadIdx.x;
  volatile __shared__ float Arow[NNODE];
  __shared__ float n1v[NEMB], n2v[NEMB];
  if (tid < NEMB) n1v[tid] = n1[v * NEMB + tid];
  if (tid >= 64 && tid < 64 + NEMB) n2v[tid - 64] = n2[v * NEMB + tid - 64];
  __syncthreads();
  for (int w = tid; w < NNODE; w += 256) {
    float d1 = 0.f, d2 = 0.f;
    const float* r1 = n1 + w * NEMB;
    const float* r2 = n2 + w * NEMB;
    for (int e = 0; e < NEMB; ++e) {
      d1 = fmaf(n1v[e], r2[e], d1);
      d2 = fmaf(n2v[e], r1[e], d2);
    }
    float a = tanhf(3.0f * (d1 - d2));
    Arow[w] = a > 0.f ? a : 0.f;
  }
  __syncthreads();
  if (tid >= 64) return;   // single wave does topk
  float sum = 1.0f;        // diagonal of A+I
  float selv[KNEI];
  int seli[KNEI];
  #pragma unroll
  for (int s = 0; s < KNEI; ++s) {
    float bv = -1.f; int bi = NNODE;
    #pragma unroll
    for (int w8 = 0; w8 < NNODE / 64; ++w8) {
      const int w = tid + 64 * w8;
      const float val = Arow[w];
      if (val > bv || (val == bv && w < bi)) { bv = val; bi = w; }
    }
    #pragma unroll
    for (int off = 32; off >= 1; off >>= 1) {
      const float ov = __shfl_down(bv, off);
      const int oi = __shfl_down(bi, off);
      if (ov > bv || (ov == bv && oi < bi)) { bv = ov; bi = oi; }
    }
    bv = __shfl(bv, 0);
    bi = __shfl(bi, 0);
    selv[s] = bv;
    seli[s] = bi;
    Arow[bi] = -2.f;
    sum += bv;
  }
  if (tid == 0) {
    const float inv = 1.0f / sum;
    #pragma unroll
    for (int s = 0; s < KNEI; ++s) {
      cols[v * NADJ + s] = seli[s];
      wts[v * NADJ + s] = selv[s] * inv;
    }
    cols[v * NADJ + KNEI] = v;
    wts[v * NADJ + KNEI] = inv;
  }
}

// ---------------------------------------------------------------- weights struct
struct ZParams {
  const float* fw[4]; const float* fb[4];
  const float* gw[4]; const float* gb[4];
};

// ---------------------------------------------------------------- pack: MFMA A-frags + bias + folded N matrices
// pA: [m(2)][s(2)][j(7)][lane(64)][e(8)] bf16   (A-frag row=l&31, k=(l>>5)*8+e)
// pBias: [m(2)][lane(64)][r(16)] f32 in D-layout
// nmat: [3][co(32)][c(32)] f32 : N0 = W0+.05(W1+W2); N1 = .95W1+.0475W2; N2 = .9025W2
__global__ __launch_bounds__(256) void pack_kernel(ZParams p, const float* __restrict__ mw,
                                                   unsigned short* __restrict__ pA,
                                                   float* __restrict__ pB,
                                                   float* __restrict__ nmat) {
  const int idx = blockIdx.x * 256 + threadIdx.x;
  if (idx < 2 * 2 * 7 * 64 * 8) {
    const int e = idx & 7;
    const int l = (idx >> 3) & 63;
    int rest = idx >> 9;
    const int j = rest % 7;
    rest /= 7;
    const int s = rest & 1;
    const int m = rest >> 1;
    const int row = l & 31;
    const int k = ((l >> 5) << 3) + e;
    const int ci = s * 16 + k;
    const int isF = (row < 16);
    const int co = m * 16 + (isF ? row : row - 16);
    const int br = co >> 3;
    const int kk = (br == 0) ? 2 : (br == 1) ? 3 : (br == 2) ? 6 : 7;
    const int jw = j - (7 - kk);
    const float* arr = isF ? p.fw[br] : p.gw[br];
    float val = (jw >= 0) ? arr[((co & 7) * NC + ci) * kk + jw] : 0.f;
    pA[idx] = f2b(val);
  } else if (idx < 2 * 2 * 7 * 64 * 8 + 2 * 64 * 16) {
    const int ib = idx - 2 * 2 * 7 * 64 * 8;
    const int r = ib & 15;
    const int l = (ib >> 4) & 63;
    const int m = ib >> 10;
    const int rr = r & 7;
    const int row = (rr & 3) + 8 * (rr >> 2) + 4 * (l >> 5);
    const int co = m * 16 + row;
    const int br = co >> 3;
    const float* arr = (r < 8) ? p.fb[br] : p.gb[br];
    pB[ib] = arr[co & 7];
  } else if (idx < 2 * 2 * 7 * 64 * 8 + 2 * 64 * 16 + 3 * NC * NC) {
    const int in_ = idx - (2 * 2 * 7 * 64 * 8 + 2 * 64 * 16);
    const int c = in_ & 31;
    const int co = (in_ >> 5) & 31;
    const int which = in_ >> 10;
    const float w0 = mw[co * 96 + c];
    const float w1 = mw[co * 96 + 32 + c];
    const float w2 = mw[co * 96 + 64 + c];
    float val;
    if (which == 0)      val = w0 + 0.05f * (w1 + w2);
    else if (which == 1) val = 0.95f * w1 + 0.0475f * w2;
    else                 val = 0.9025f * w2;
    nmat[in_] = val;
  }
}

// ---------------------------------------------------------------- Z: MFMA gated inception conv -> bf16 z
#define XT_PITCH 40
__global__ __launch_bounds__(256) void zmfma_kernel(
    const float* __restrict__ x, const unsigned short* __restrict__ pA,
    const float* __restrict__ pBias, unsigned short* __restrict__ z) {
  __shared__ unsigned short xt[176 * XT_PITCH];
  const int n = blockIdx.x;
  const int b = blockIdx.y;
  const int tid = threadIdx.x;
  for (int i = tid; i < NC * 176; i += 256) {
    const int ci = i / 176;
    const int t = i - ci * 176;
    float v = (t < NT) ? x[((b * NC + ci) * NNODE + n) * NT + t] : 0.f;
    xt[t * XT_PITCH + ci] = f2b(v);
  }
  __syncthreads();
  const int w = tid >> 6, l = tid & 63;
  const int jc = l & 31, h = l >> 5;
  const int m = w & 1;
  const int ntBase = (w >> 1) ? 3 : 0;
  const int ntCount = (w >> 1) ? 2 : 3;
  bf16x8 aF[2][7];
  #pragma unroll
  for (int s = 0; s < 2; ++s)
    #pragma unroll
    for (int j = 0; j < 7; ++j)
      aF[s][j] = *reinterpret_cast<const bf16x8*>(
          pA + ((((m * 2 + s) * 7 + j) << 6) + l) * 8);
  f32x16 accBias;
  const float* pb = pBias + (m * 64 + l) * 16;
  #pragma unroll
  for (int r = 0; r < 16; ++r) accBias[r] = pb[r];

  for (int nt = 0; nt < ntCount; ++nt) {
    const int t0 = (ntBase + nt) * 32;
    f32x16 acc = accBias;
    #pragma unroll
    for (int j = 0; j < 7; ++j) {
      const int row = t0 + jc + 2 * j;
      const unsigned short* bp = &xt[row * XT_PITCH + h * 8];
      bf16x8 b0 = *reinterpret_cast<const bf16x8*>(bp);
      bf16x8 b1 = *reinterpret_cast<const bf16x8*>(bp + 16);
      acc = __builtin_amdgcn_mfma_f32_32x32x16_bf16(aF[0][j], b0, acc, 0, 0, 0);
      acc = __builtin_amdgcn_mfma_f32_32x32x16_bf16(aF[1][j], b1, acc, 0, 0, 0);
    }
    const int t = t0 + jc;
    if (t < NTO) {
      #pragma unroll
      for (int r = 0; r < 8; ++r) {
        const float f = fast_tanh(acc[r]);
        const float g = fast_sigmoid(acc[r + 8]);
        const int row = (r & 3) + 8 * (r >> 2) + 4 * h;
        const int co = m * 16 + row;
        z[((b * NC + co) * NNODE + n) * NTO + t] = f2b(f * g);
      }
    }
  }
}

// ---------------------------------------------------------------- K1: m = N1*z + N2*gather(z)   (bf16 in/out)
__global__ __launch_bounds__(256) void k1_kernel(
    const unsigned short* __restrict__ z, const int* __restrict__ cols,
    const float* __restrict__ wts, const float* __restrict__ nmat,
    unsigned short* __restrict__ m) {
  const int i = blockIdx.x * 256 + threadIdx.x;   // (b, v, q)
  const int q = i % NQ;
  const int r = i / NQ;
  const int v = r % NNODE;
  const int b = r / NNODE;
  int off[NADJ]; float wv[NADJ];
  #pragma unroll
  for (int s = 0; s < NADJ; ++s) {
    off[s] = cols[v * NADJ + s] * NTO + 4 * q;
    wv[s] = wts[v * NADJ + s];
  }
  const int voff = v * NTO + 4 * q;
  float4 acc[NC];
  #pragma unroll
  for (int co = 0; co < NC; ++co) acc[co] = make_float4(0.f, 0.f, 0.f, 0.f);
  const float* n1m = nmat + NC * NC;
  const float* n2m = nmat + 2 * NC * NC;
  for (int c = 0; c < NC; ++c) {
    const unsigned short* zc = z + (size_t)(b * NC + c) * NNODE * NTO;
    const float4 zv = bf4load(zc + voff);
    float4 us = make_float4(0.f, 0.f, 0.f, 0.f);
    #pragma unroll
    for (int s = 0; s < NADJ; ++s) {
      const float4 t = bf4load(zc + off[s]);
      us.x = fmaf(wv[s], t.x, us.x); us.y = fmaf(wv[s], t.y, us.y);
      us.z = fmaf(wv[s], t.z, us.z); us.w = fmaf(wv[s], t.w, us.w);
    }
    #pragma unroll
    for (int co = 0; co < NC; ++co) {
      const float a1 = n1m[co * NC + c];
      const float a2 = n2m[co * NC + c];
      acc[co].x = fmaf(a1, zv.x, fmaf(a2, us.x, acc[co].x));
      acc[co].y = fmaf(a1, zv.y, fmaf(a2, us.y, acc[co].y));
      acc[co].z = fmaf(a1, zv.z, fmaf(a2, us.z, acc[co].z));
      acc[co].w = fmaf(a1, zv.w, fmaf(a2, us.w, acc[co].w));
    }
  }
  #pragma unroll
  for (int co = 0; co < NC; ++co) {
    ushort4 o;
    o.x = f2b(acc[co].x); o.y = f2b(acc[co].y);
    o.z = f2b(acc[co].z); o.w = f2b(acc[co].w);
    *reinterpret_cast<ushort4*>(m + (size_t)(b * NC + co) * NNODE * NTO + voff) = o;
  }
}

// ---------------------------------------------------------------- K2: out = N0*z + gather(m) + mb + x, + stats
__global__ __launch_bounds__(256) void k2_kernel(
    const unsigned short* __restrict__ z, const unsigned short* __restrict__ m,
    const float* __restrict__ x, const int* __restrict__ cols,
    const float* __restrict__ wts, const float* __restrict__ nmat,
    const float* __restrict__ mb, float* __restrict__ out,
    float* __restrict__ stats) {
  const int i = blockIdx.x * 256 + threadIdx.x;   // (b, v, q)
  const int q = i % NQ;
  const int r = i / NQ;
  const int v = r % NNODE;
  const int b = r / NNODE;
  int off[NADJ]; float wv[NADJ];
  #pragma unroll
  for (int s = 0; s < NADJ; ++s) {
    off[s] = cols[v * NADJ + s] * NTO + 4 * q;
    wv[s] = wts[v * NADJ + s];
  }
  const int voff = v * NTO + 4 * q;
  float4 acc[NC];
  #pragma unroll
  for (int co = 0; co < NC; ++co) {
    const unsigned short* mc = m + (size_t)(b * NC + co) * NNODE * NTO;
    const float bb = mb[co];
    float4 a = make_float4(bb, bb, bb, bb);
    #pragma unroll
    for (int s = 0; s < NADJ; ++s) {
      const float4 t = bf4load(mc + off[s]);
      a.x = fmaf(wv[s], t.x, a.x); a.y = fmaf(wv[s], t.y, a.y);
      a.z = fmaf(wv[s], t.z, a.z); a.w = fmaf(wv[s], t.w, a.w);
    }
    acc[co] = a;
  }
  const float* n0m = nmat;
  for (int c = 0; c < NC; ++c) {
    const float4 zv = bf4load(z + (size_t)(b * NC + c) * NNODE * NTO + voff);
    #pragma unroll
    for (int co = 0; co < NC; ++co) {
      const float a0 = n0m[co * NC + c];
      acc[co].x = fmaf(a0, zv.x, acc[co].x);
      acc[co].y = fmaf(a0, zv.y, acc[co].y);
      acc[co].z = fmaf(a0, zv.z, acc[co].z);
      acc[co].w = fmaf(a0, zv.w, acc[co].w);
    }
  }
  float s1 = 0.f, s2 = 0.f;
  #pragma unroll
  for (int co = 0; co < NC; ++co) {
    const int xb = ((b * NC + co) * NNODE + v) * NT + 12 + 4 * q;
    const float4 xr = *reinterpret_cast<const float4*>(x + xb);
    float4 o;
    o.x = acc[co].x + xr.x; o.y = acc[co].y + xr.y;
    o.z = acc[co].z + xr.z; o.w = acc[co].w + xr.w;
    const int ob = ((b * NC + co) * NNODE + v) * NTO + 4 * q;
    *reinterpret_cast<float4*>(out + ob) = o;
    s1 += o.x + o.y + o.z + o.w;
    s2 += o.x * o.x + o.y * o.y + o.z * o.z + o.w * o.w;
  }
  #pragma unroll
  for (int offs = 32; offs >= 1; offs >>= 1) {
    s1 += __shfl_down(s1, offs);
    s2 += __shfl_down(s2, offs);
  }
  __shared__ float r1[4], r2[4];
  const int lane = threadIdx.x & 63, wv_ = threadIdx.x >> 6;
  if (lane == 0) { r1[wv_] = s1; r2[wv_] = s2; }
  __syncthreads();
  if (threadIdx.x == 0) {   // b uniform per block (19968 threads per b = 78 blocks)
    atomicAdd(&stats[b * 2], r1[0] + r1[1] + r1[2] + r1[3]);
    atomicAdd(&stats[b * 2 + 1], r2[0] + r2[1] + r2[2] + r2[3]);
  }
}

// ---------------------------------------------------------------- L: layernorm (in-place on out)
__global__ __launch_bounds__(256) void ln_kernel(
    float* __restrict__ out, const float* __restrict__ lnw,
    const float* __restrict__ lnb, const int* __restrict__ idx,
    const float* __restrict__ stats) {
  const int i = blockIdx.x * 256 + threadIdx.x;
  const int q = i % NQ;
  const int r = i / NQ;
  const int v = r % NNODE;
  const int r2 = r / NNODE;
  const int co = r2 % NC;
  const int b = r2 / NC;
  const float invM = 1.0f / (float)(NC * NNODE * NTO);
  const float mean = stats[b * 2] * invM;
  const float var = stats[b * 2 + 1] * invM - mean * mean;
  const float rs = rsqrtf(var + 1e-5f);
  float4 o = *reinterpret_cast<const float4*>(out + 4 * i);
  const int iv = idx[v];
  const int lb = (co * NNODE + iv) * NTO + 4 * q;
  const float4 w = *reinterpret_cast<const float4*>(lnw + lb);
  const float4 bb = *reinterpret_cast<const float4*>(lnb + lb);
  o.x = (o.x - mean) * rs * w.x + bb.x;
  o.y = (o.y - mean) * rs * w.y + bb.y;
  o.z = (o.z - mean) * rs * w.z + bb.z;
  o.w = (o.w - mean) * rs * w.w + bb.w;
  *reinterpret_cast<float4*>(out + 4 * i) = o;
}

// ---------------------------------------------------------------- launch
extern "C" void kernel_launch(void* const* d_in, const int* in_sizes, int n_in,
                              void* d_out, int out_size, void* d_ws, size_t ws_size,
                              hipStream_t stream) {
  const float* x    = (const float*)d_in[0];
  const int*   idx  = (const int*)d_in[1];
  const float* emb1 = (const float*)d_in[2];
  const float* emb2 = (const float*)d_in[3];
  const float* W1   = (const float*)d_in[4];
  const float* b1   = (const float*)d_in[5];
  const float* W2   = (const float*)d_in[6];
  const float* b2   = (const float*)d_in[7];
  const float* mlp_w = (const float*)d_in[24];
  const float* mlp_b = (const float*)d_in[25];
  const float* ln_w = (const float*)d_in[26];
  const float* ln_b = (const float*)d_in[27];

  char* ws = (char*)d_ws;
  float* n1    = (float*)(ws);
  float* n2    = (float*)(ws + (128 << 10));
  int*   cols  = (int*)  (ws + (256 << 10));
  float* wts   = (float*)(ws + (320 << 10));
  float* stats = (float*)(ws + (384 << 10));
  unsigned short* pA = (unsigned short*)(ws + (400 << 10));   // 28,672 B
  float* pBias = (float*)(ws + (440 << 10));                  // 8,192 B
  float* nmat  = (float*)(ws + (456 << 10));                  // 12,288 B
  const size_t zbytes = (size_t)NB * NC * NNODE * NTO * 2;    // bf16
  unsigned short* z = (unsigned short*)(ws + (512 << 10));
  unsigned short* m = (unsigned short*)(ws + (512 << 10) + zbytes);

  ZParams zp;
  for (int k = 0; k < 4; ++k) {
    zp.fw[k] = (const float*)d_in[8 + 2 * k];
    zp.fb[k] = (const float*)d_in[9 + 2 * k];
    zp.gw[k] = (const float*)d_in[16 + 2 * k];
    zp.gb[k] = (const float*)d_in[17 + 2 * k];
  }

  hipMemsetAsync(stats, 0, 2 * NB * sizeof(float), stream);
  g1_kernel<<<NNODE, 128, 0, stream>>>(emb1, emb2, W1, b1, W2, b2, idx, n1, n2);
  g2_kernel<<<NNODE, 256, 0, stream>>>(n1, n2, cols, wts);
  pack_kernel<<<80, 256, 0, stream>>>(zp, mlp_w, pA, pBias, nmat);
  zmfma_kernel<<<dim3(NNODE, NB), 256, 0, stream>>>(x, pA, pBias, z);
  const int bvqBlocks = NB * NNODE * NQ / 256;   // 2496
  k1_kernel<<<bvqBlocks, 256, 0, stream>>>(z, cols, wts, nmat, m);
  k2_kernel<<<bvqBlocks, 256, 0, stream>>>(z, m, x, cols, wts, nmat, mlp_b,
                                           (float*)d_out, stats);
  ln_kernel<<<NB * NC * NNODE * NQ / 256, 256, 0, stream>>>((float*)d_out, ln_w, ln_b,
                                                            idx, stats);
}